// Round 7
// baseline (16794.061 us; speedup 1.0000x reference)
//
#include <hip/hip_runtime.h>
#include <stdint.h>

typedef unsigned int u32;
typedef unsigned long long u64;
typedef unsigned short u16;
typedef __attribute__((ext_vector_type(8))) short s8;
typedef __attribute__((ext_vector_type(4))) float f4;

#define NWG 256
#define TPB 512
#define NB 64      // batch
#define TT 400     // seq len
#define EE 300     // embed dim
#define HEN 512    // encoder hidden
#define HD 1024    // decoder hidden
#define VV 50000   // vocab
#define DEC 80     // decode steps
#define NTL 3125   // VV/16 n-tiles
#define NTLP 3136  // padded row stride for batch-major prt
#define LCAP 512   // rescue list capacity
#define EOFF 39168             // enc LDS: [0,EOFF) weights, [EOFF,+16K) combine
#define LGOFF 131072           // dec LDS: [0,128K) hA, [128K,+16K) combine/rescue/hsq
#define DSZ (LGOFF + 16384)
#define RESC 0.00837f          // 2^-8 * 1.002 * 2.09 safety (bf16 h + bf16 w + fp32 acc)

// barrier state word offsets inside p.bar
#define BD_GRP   0      // enc dir barrier: 16 lines x 64
#define BD_ROOT  1024   // + dir*64
#define BD_EPO   1152   // + dir*64
#define BX_GRP   1280   // dec barriers: 16 lines x 64
#define BX_ROOT  2304
#define BX_EPO   2368
#define BAR_WORDS 2432

// COHERENCE PROTOCOL (coop mode):
//  - mutable data WRITTEN each step goes through cst (sc0/sc1 write-through to
//    the coherence point), then a fence-free tree barrier.
//  - readers use PLAIN CACHED loads on FRESH buffers (one per step, never
//    touched before) -> first touch misses in L1/L2 and fills from LLC with
//    the cst-written data. Full cache BW, no fences, no cache-bypass reads.
//  - small irregular state (tok, prt) stays on cld (uncached coherent read).
// Fallback mode (workspace too small): round-6 per-phase dispatches, plain
// loads/stores, dispatch boundaries provide coherence.

struct P {
  const int* texts; const int* len; const float* emb;
  const float* ewih0; const float* ewhh0; const float* ebih0; const float* ebhh0;
  const float* ewih1; const float* ewhh1; const float* ebih1; const float* ebhh1;
  const float* dwih; const float* dwhh; const float* dbih; const float* dbhh;
  const float* outw; const float* outb;
  float* out;
  u16* owbf; float* xT; u64* prt; int* tok; float* wn; u32* bar;
  // coop-mode rotated buffers
  float* hrF; float* hrB;   // (TT+1) x HEN*NB each
  float* hTdR;              // (DEC+1) x HD*NB
  u16* hbfR;                // DEC x NB*HD
  // fallback-mode single buffers
  float* hTf; float* hTb; float* hTd; u16* hbf;
};

__device__ __forceinline__ float cld(const float* a) {
  return __hip_atomic_load(const_cast<float*>(a), __ATOMIC_RELAXED, __HIP_MEMORY_SCOPE_AGENT);
}
__device__ __forceinline__ void cst(float* a, float v) {
  __hip_atomic_store(a, v, __ATOMIC_RELAXED, __HIP_MEMORY_SCOPE_AGENT);
}
__device__ __forceinline__ u64 cld(const u64* a) {
  return __hip_atomic_load(const_cast<u64*>(a), __ATOMIC_RELAXED, __HIP_MEMORY_SCOPE_AGENT);
}
__device__ __forceinline__ void cst(u64* a, u64 v) {
  __hip_atomic_store(a, v, __ATOMIC_RELAXED, __HIP_MEMORY_SCOPE_AGENT);
}
__device__ __forceinline__ int cld(const int* a) {
  return __hip_atomic_load(const_cast<int*>(a), __ATOMIC_RELAXED, __HIP_MEMORY_SCOPE_AGENT);
}
__device__ __forceinline__ void cst(int* a, int v) {
  __hip_atomic_store(a, v, __ATOMIC_RELAXED, __HIP_MEMORY_SCOPE_AGENT);
}
__device__ __forceinline__ void cst(u16* a, u16 v) {
  __hip_atomic_store(a, v, __ATOMIC_RELAXED, __HIP_MEMORY_SCOPE_AGENT);
}

// Fence-free tree barrier (cst/atomics are already at the coherence point).
__device__ __forceinline__ void gbarx(u32* grp, u32* root, u32* epo,
                                      u32 e, u32 gsz, u32 nroot) {
  __syncthreads();
  if (threadIdx.x == 0) {
    u32 old = __hip_atomic_fetch_add(grp, 1u, __ATOMIC_RELAXED, __HIP_MEMORY_SCOPE_AGENT);
    if (old == e * gsz + (gsz - 1u)) {
      u32 r = __hip_atomic_fetch_add(root, 1u, __ATOMIC_RELAXED, __HIP_MEMORY_SCOPE_AGENT);
      if (r == e * nroot + (nroot - 1u))
        __hip_atomic_store(epo, e + 1u, __ATOMIC_RELAXED, __HIP_MEMORY_SCOPE_AGENT);
    }
    while (__hip_atomic_load(epo, __ATOMIC_RELAXED, __HIP_MEMORY_SCOPE_AGENT) < e + 1u)
      __builtin_amdgcn_s_sleep(8);
  }
  __syncthreads();
}

__device__ __forceinline__ u32 fkey(float v) {
  u32 u = __float_as_uint(v);
  return (u & 0x80000000u) ? ~u : (u | 0x80000000u);
}
__device__ __forceinline__ u16 f2bf(float f) {   // RNE fp32->bf16
  u32 u = __float_as_uint(f);
  u32 r = u + 0x7FFFu + ((u >> 16) & 1u);
  return (u16)(r >> 16);
}
__device__ __forceinline__ float sigm(float x) { return 1.f / (1.f + expf(-x)); }

// ---- shared GRU epilogue: two-stage partial combine in 16KB LDS + activations
template<bool COH>
__device__ __forceinline__ void gru_combine_epi(
    float* pb, const f4& ar, const f4& az, const f4& ax, const f4& ah,
    int jjb, int HL, const float* bih, const float* bhh,
    const float* hc, float* ho, int mask_t, const int* lenp, u16* hbf_out)
{
  const int tid = threadIdx.x, lane = tid & 63, wv = tid >> 6;
  const int wl = wv & 3;
  if (wv < 4) {
    #pragma unroll
    for (int j = 0; j < 4; j++) {
      pb[((wl * 16 + j * 4 + 0) * 64) + lane] = ar[j];
      pb[((wl * 16 + j * 4 + 1) * 64) + lane] = az[j];
      pb[((wl * 16 + j * 4 + 2) * 64) + lane] = ax[j];
      pb[((wl * 16 + j * 4 + 3) * 64) + lane] = ah[j];
    }
  }
  __syncthreads();
  if (wv >= 4) {
    #pragma unroll
    for (int j = 0; j < 4; j++) {
      pb[((wl * 16 + j * 4 + 0) * 64) + lane] += ar[j];
      pb[((wl * 16 + j * 4 + 1) * 64) + lane] += az[j];
      pb[((wl * 16 + j * 4 + 2) * 64) + lane] += ax[j];
      pb[((wl * 16 + j * 4 + 3) * 64) + lane] += ah[j];
    }
  }
  __syncthreads();
  if (tid < 256) {
    int b = tid & 63, j = tid >> 6;
    int jj = jjb + j;
    float r = 0, z = 0, xn = 0, hn = 0;
    #pragma unroll
    for (int w = 0; w < 4; w++) {
      int base = ((w * 16 + j * 4) * 64) + b;
      r  += pb[base];
      z  += pb[base + 64];
      xn += pb[base + 128];
      hn += pb[base + 192];
    }
    r = sigm(r + bih[jj] + bhh[jj]);
    z = sigm(z + bih[HL + jj] + bhh[HL + jj]);
    float nn = tanhf(xn + bih[2 * HL + jj] + r * (hn + bhh[2 * HL + jj]));
    float hold = hc[(size_t)jj * NB + b];          // plain (fresh buffer / intra-dispatch)
    float hv = (1.f - z) * nn + z * hold;
    if (lenp && mask_t >= lenp[b]) hv = hold;
    if (COH) cst(ho + (size_t)jj * NB + b, hv);
    else     ho[(size_t)jj * NB + b] = hv;
    if (hbf_out) {
      if (COH) cst(hbf_out + (size_t)b * HD + jj, f2bf(hv));
      else     hbf_out[(size_t)b * HD + jj] = f2bf(hv);
    }
  }
}

// Encoder step body: weights in LDS [k][12]; x/h plain cached loads (batched x8)
template<bool COH>
__device__ __forceinline__ void enc_step_body(
    char* smem, int jjb, const float* xsrc,
    const float* bih, const float* bhh,
    const float* __restrict__ hc, float* ho, int te, const int* lenp)
{
  const int tid = threadIdx.x, lane = tid & 63, wv = tid >> 6;
  const float* lw = (const float*)smem;
  const int KT = EE + HEN;
  const int vs = (wv * KT) >> 3, ve = ((wv + 1) * KT) >> 3;
  f4 ar = {0,0,0,0}, az = {0,0,0,0}, ax = {0,0,0,0}, ah = {0,0,0,0};
  const int xe = ve < EE ? ve : EE;
  int k = vs;
  for (; k + 8 <= xe; k += 8) {
    float xv[8];
    #pragma unroll
    for (int u = 0; u < 8; u++) xv[u] = xsrc[(size_t)(k + u) * NB + lane];
    #pragma unroll
    for (int u = 0; u < 8; u++) {
      const float* wp = lw + (k + u) * 12;
      f4 w0 = *(const f4*)wp; f4 w1 = *(const f4*)(wp + 4); f4 w2 = *(const f4*)(wp + 8);
      ar += xv[u] * w0; az += xv[u] * w1; ax += xv[u] * w2;
    }
  }
  for (; k < xe; k++) {
    float xv = xsrc[(size_t)k * NB + lane];
    const float* wp = lw + k * 12;
    f4 w0 = *(const f4*)wp; f4 w1 = *(const f4*)(wp + 4); f4 w2 = *(const f4*)(wp + 8);
    ar += xv * w0; az += xv * w1; ax += xv * w2;
  }
  k = vs > EE ? vs : EE;
  for (; k + 8 <= ve; k += 8) {
    float hv[8];
    #pragma unroll
    for (int u = 0; u < 8; u++) hv[u] = hc[(size_t)(k + u - EE) * NB + lane];
    #pragma unroll
    for (int u = 0; u < 8; u++) {
      const float* wp = lw + (k + u) * 12;
      f4 w0 = *(const f4*)wp; f4 w1 = *(const f4*)(wp + 4); f4 w2 = *(const f4*)(wp + 8);
      ar += hv[u] * w0; az += hv[u] * w1; ah += hv[u] * w2;
    }
  }
  for (; k < ve; k++) {
    float hv = hc[(size_t)(k - EE) * NB + lane];
    const float* wp = lw + k * 12;
    f4 w0 = *(const f4*)wp; f4 w1 = *(const f4*)(wp + 4); f4 w2 = *(const f4*)(wp + 8);
    ar += hv * w0; az += hv * w1; ah += hv * w2;
  }
  gru_combine_epi<COH>((float*)(smem + EOFF), ar, az, ax, ah, jjb, HEN,
                       bih, bhh, hc, ho, te, lenp, nullptr);
}

__device__ __forceinline__ void enc_stage_weights(char* smem, int dir, int ejjb,
                                                  const P& p) {
  const int tid = threadIdx.x, lane = tid & 63, wv = tid >> 6;
  const float* wih = dir ? p.ewih1 : p.ewih0;
  const float* whh = dir ? p.ewhh1 : p.ewhh0;
  float* lw = (float*)smem;
  for (int c = wv; c < 12; c += 8) {
    int g = c >> 2, j = c & 3;
    const float* sx = wih + (size_t)(g * HEN + ejjb + j) * EE;
    for (int k = lane; k < EE; k += 64) lw[k * 12 + c] = sx[k];
    const float* sh = whh + (size_t)(g * HEN + ejjb + j) * HEN;
    for (int k = lane; k < HEN; k += 64) lw[(EE + k) * 12 + c] = sh[k];
  }
}

// Decoder GRU body: weights cached global; h plain (batched x4); tok cld/plain
template<bool COH>
__device__ __forceinline__ void dec_gru_body(
    const P& p, float* pb, int jjb,
    const float* __restrict__ hc, float* ho, u16* hbf_out)
{
  const int tid = threadIdx.x, lane = tid & 63, wv = tid >> 6;
  const float* wih = p.dwih; const float* whh = p.dwhh;
  const int KT = EE + HD;
  const int vs = (wv * KT) >> 3, ve = ((wv + 1) * KT) >> 3;
  f4 ar = {0,0,0,0}, az = {0,0,0,0}, ax = {0,0,0,0}, ah = {0,0,0,0};
  const int xe = ve < EE ? ve : EE;
  if (vs < EE) {
    int tk = COH ? cld(p.tok + lane) : p.tok[lane];
    const float* xr = p.emb + (size_t)tk * EE;
    int k = vs;
    for (; k + 4 <= xe; k += 4) {
      float xv[4];
      #pragma unroll
      for (int u = 0; u < 4; u++) xv[u] = xr[k + u];
      #pragma unroll
      for (int u = 0; u < 4; u++) {
        #pragma unroll
        for (int j = 0; j < 4; j++) {
          int jj = jjb + j;
          ar[j] = fmaf(xv[u], wih[(size_t)jj * EE + k + u], ar[j]);
          az[j] = fmaf(xv[u], wih[(size_t)(HD + jj) * EE + k + u], az[j]);
          ax[j] = fmaf(xv[u], wih[(size_t)(2 * HD + jj) * EE + k + u], ax[j]);
        }
      }
    }
    for (; k < xe; k++) {
      float xv = xr[k];
      #pragma unroll
      for (int j = 0; j < 4; j++) {
        int jj = jjb + j;
        ar[j] = fmaf(xv, wih[(size_t)jj * EE + k], ar[j]);
        az[j] = fmaf(xv, wih[(size_t)(HD + jj) * EE + k], az[j]);
        ax[j] = fmaf(xv, wih[(size_t)(2 * HD + jj) * EE + k], ax[j]);
      }
    }
  }
  int hs = vs - EE; if (hs < 0) hs = 0;
  const int he = ve - EE;
  int k = hs;
  for (; k + 4 <= he; k += 4) {
    float hv[4];
    #pragma unroll
    for (int u = 0; u < 4; u++) hv[u] = hc[(size_t)(k + u) * NB + lane];
    #pragma unroll
    for (int u = 0; u < 4; u++) {
      #pragma unroll
      for (int j = 0; j < 4; j++) {
        int jj = jjb + j;
        ar[j] = fmaf(hv[u], whh[(size_t)jj * HD + k + u], ar[j]);
        az[j] = fmaf(hv[u], whh[(size_t)(HD + jj) * HD + k + u], az[j]);
        ah[j] = fmaf(hv[u], whh[(size_t)(2 * HD + jj) * HD + k + u], ah[j]);
      }
    }
  }
  for (; k < he; k++) {
    float hv = hc[(size_t)k * NB + lane];
    #pragma unroll
    for (int j = 0; j < 4; j++) {
      int jj = jjb + j;
      ar[j] = fmaf(hv, whh[(size_t)jj * HD + k], ar[j]);
      az[j] = fmaf(hv, whh[(size_t)(HD + jj) * HD + k], az[j]);
      ah[j] = fmaf(hv, whh[(size_t)(2 * HD + jj) * HD + k], ah[j]);
    }
  }
  gru_combine_epi<COH>(pb, ar, az, ax, ah, jjb, HD, p.dbih, p.dbhh,
                       hc, ho, -1, nullptr, hbf_out);
}

// Decoder logits body: hbf_src staged to swizzled LDS (plain cached reads),
// bf16 MFMA vs owbf stream, certified (lo,up) keys to batch-major prt.
template<bool COH>
__device__ __forceinline__ void dec_logits_body(const P& p, char* smem,
                                                const u16* hbf_src) {
  const int wg = blockIdx.x, tid = threadIdx.x;
  const int lane = tid & 63, wv = tid >> 6;
  u16* hA = (u16*)smem;                 // [64][128 chunks of 16B], swizzled
  float* hsq = (float*)(smem + LGOFF);  // [64]
  const int l15 = lane & 15, quad = lane >> 4;
  const int gw = wg * 8 + wv;
  const bool two = (gw + 2048) < NTL;
  if (tid < 64) hsq[tid] = 0.f;
  __syncthreads();
  for (int i = tid; i < 8192; i += TPB) {       // stage full hbf + ||h||^2
    int r = i >> 7, c = i & 127;
    uint4 q = *(const uint4*)(hbf_src + (size_t)r * HD + c * 8);
    *(uint4*)(hA + (size_t)r * 1024 + ((c ^ (r & 7)) * 8)) = q;
    u32 uu[4] = {q.x, q.y, q.z, q.w};
    float sq = 0.f;
    #pragma unroll
    for (int t2 = 0; t2 < 4; t2++) {
      float lo = __uint_as_float(uu[t2] << 16);
      float hi = __uint_as_float(uu[t2] & 0xffff0000u);
      sq = fmaf(lo, lo, fmaf(hi, hi, sq));
    }
    atomicAdd(&hsq[r], sq);
  }
  __syncthreads();
  f4 acc0[4], acc1[4];
  #pragma unroll
  for (int m = 0; m < 4; m++) {
    #pragma unroll
    for (int r = 0; r < 4; r++) { acc0[m][r] = 0.f; acc1[m][r] = 0.f; }
  }
  const u16* bp0 = p.owbf + (size_t)(gw * 16 + l15) * HD + quad * 8;
  const u16* bp1 = bp0 + (size_t)2048 * 16 * HD;
  const int x7 = l15 & 7;
  const u16* hrow = hA + l15 * 1024;
  #pragma unroll 4
  for (int kc = 0; kc < 32; kc++) {
    int ci = ((kc * 4 + quad) ^ x7) * 8;
    s8 b0 = *(const s8*)(bp0 + kc * 32);
    s8 a0 = *(const s8*)(hrow + ci);
    s8 a1 = *(const s8*)(hrow + 16384 + ci);
    s8 a2 = *(const s8*)(hrow + 32768 + ci);
    s8 a3 = *(const s8*)(hrow + 49152 + ci);
    acc0[0] = __builtin_amdgcn_mfma_f32_16x16x32_bf16(a0, b0, acc0[0], 0, 0, 0);
    acc0[1] = __builtin_amdgcn_mfma_f32_16x16x32_bf16(a1, b0, acc0[1], 0, 0, 0);
    acc0[2] = __builtin_amdgcn_mfma_f32_16x16x32_bf16(a2, b0, acc0[2], 0, 0, 0);
    acc0[3] = __builtin_amdgcn_mfma_f32_16x16x32_bf16(a3, b0, acc0[3], 0, 0, 0);
    if (two) {
      s8 b1 = *(const s8*)(bp1 + kc * 32);
      acc1[0] = __builtin_amdgcn_mfma_f32_16x16x32_bf16(a0, b1, acc1[0], 0, 0, 0);
      acc1[1] = __builtin_amdgcn_mfma_f32_16x16x32_bf16(a1, b1, acc1[1], 0, 0, 0);
      acc1[2] = __builtin_amdgcn_mfma_f32_16x16x32_bf16(a2, b1, acc1[2], 0, 0, 0);
      acc1[3] = __builtin_amdgcn_mfma_f32_16x16x32_bf16(a3, b1, acc1[3], 0, 0, 0);
    }
  }
  float hroot[4][4];
  #pragma unroll
  for (int m = 0; m < 4; m++)
    #pragma unroll
    for (int r = 0; r < 4; r++)
      hroot[m][r] = sqrtf(hsq[m * 16 + quad * 4 + r]);
  auto epi = [&](int nt, f4* acc) {
    int col = nt * 16 + l15;
    float bias = p.outb[col];
    float wnc = p.wn[col];
    #pragma unroll
    for (int m = 0; m < 4; m++) {
      #pragma unroll
      for (int r = 0; r < 4; r++) {
        float v = acc[m][r] + bias;
        float e = RESC * hroot[m][r] * wnc + 1e-5f;
        u32 klo = fkey(v - e), kup = fkey(v + e);
        #pragma unroll
        for (int d = 1; d < 16; d <<= 1) {
          u32 ol = __shfl_xor(klo, d); if (ol > klo) klo = ol;
          u32 ou = __shfl_xor(kup, d); if (ou > kup) kup = ou;
        }
        if (l15 == 0) {
          u64 key = ((u64)klo << 32) | kup;
          u64* dst = p.prt + (size_t)(m * 16 + quad * 4 + r) * NTLP + nt;
          if (COH) cst(dst, key); else *dst = key;
        }
      }
    }
  };
  epi(gw, acc0);
  if (two) epi(gw + 2048, acc1);
}

// Decoder rescue body (wg b): threshold T = max lo; exact fp32 rescue.
template<bool COH>
__device__ __forceinline__ void dec_rescue_body(const P& p, char* smem,
                                                const float* ho, int s, int b) {
  const int tid = threadIdx.x;
  const int lane = tid & 63, wv = tid >> 6;
  char* ms = smem + LGOFF;
  float* hb = (float*)ms;                   // [1024] exact fp32 h
  u64* red = (u64*)(ms + 4096);             // [8]
  u64* gmp = (u64*)(ms + 4160);
  u64* bestp = (u64*)(ms + 4168);
  int* ncp = (int*)(ms + 4176);
  int* list = (int*)(ms + 4192);            // [LCAP]
  for (int i = tid; i < HD; i += TPB) hb[i] = ho[(size_t)i * NB + b];
  if (tid == 0) { *bestp = 0ull; *ncp = 0; }
  __syncthreads();
  u64 pv[7];
  u64 mx = 0;
  #pragma unroll
  for (int i = 0; i < 7; i++) {
    int nt = tid + i * TPB;
    pv[i] = 0ull;
    if (nt < NTL) {
      const u64* src = p.prt + (size_t)b * NTLP + nt;
      pv[i] = COH ? cld(src) : *src;
    }
    if (pv[i] > mx) mx = pv[i];
  }
  #pragma unroll
  for (int d = 1; d < 64; d <<= 1) { u64 o = __shfl_xor(mx, d); if (o > mx) mx = o; }
  if (lane == 0) red[wv] = mx;
  __syncthreads();
  if (tid == 0) {
    u64 g = red[0];
    for (int w2 = 1; w2 < 8; w2++) if (red[w2] > g) g = red[w2];
    *gmp = g;
  }
  __syncthreads();
  const u32 thr = (u32)(*gmp >> 32);
  #pragma unroll
  for (int i = 0; i < 7; i++) {
    if ((u32)pv[i] >= thr) {
      int ix = atomicAdd(ncp, 1);
      if (ix < LCAP) list[ix] = tid + i * TPB;
    }
  }
  __syncthreads();
  int total = *ncp;
  int nc = total < LCAP ? total : LCAP;
  const int c16 = tid >> 5, seg = tid & 31;
  u64 lb = 0;
  auto rescue = [&](int nt) {
    int v = nt * 16 + c16;
    const float* wr = p.outw + (size_t)v * HD;
    float sm = 0.f;
    #pragma unroll 8
    for (int i = 0; i < 32; i++) {
      int k = seg + 32 * i;
      sm = fmaf(hb[k], wr[k], sm);
    }
    #pragma unroll
    for (int d = 1; d < 32; d <<= 1) sm += __shfl_xor(sm, d);
    if (seg == 0) {
      float lg = sm + p.outb[v];
      u64 k2 = ((u64)fkey(lg) << 32) | (~(u32)v);   // ~v: lowest idx wins ties
      if (k2 > lb) lb = k2;
    }
  };
  for (int ci = 0; ci < nc; ci++) rescue(list[ci]);
  if (total > LCAP) {
    for (int nt = 0; nt < NTL; nt++) {
      const u64* src = p.prt + (size_t)b * NTLP + nt;
      u64 v = COH ? cld(src) : *src;
      if ((u32)v >= thr) rescue(nt);
    }
  }
  if (seg == 0 && lb) atomicMax((unsigned long long*)bestp, lb);
  __syncthreads();
  if (tid == 0) {
    u32 v = ~(u32)(*bestp);
    if (COH) cst(p.tok + b, (int)v); else p.tok[b] = (int)v;
    p.out[b * DEC + s] = (float)v;
  }
}

// ================= prep: one-time (plain dispatch) =================
__global__ void __launch_bounds__(TPB, 2) prep_kernel(P p) {
  const int wg = blockIdx.x, tid = threadIdx.x;
  const int lane = tid & 63, wv = tid >> 6;
  const int gtid = wg * TPB + tid;
  int gwv = wg * 8 + wv;
  for (int v = gwv; v < VV; v += 2048) {
    const float* wr = p.outw + (size_t)v * HD + lane * 16;
    u16* dst = p.owbf + (size_t)v * HD + lane * 16;
    float sa = 0.f;
    u32 pk[8];
    #pragma unroll
    for (int q = 0; q < 4; q++) {
      float4 f = *(const float4*)(wr + q * 4);
      sa += f.x * f.x + f.y * f.y + f.z * f.z + f.w * f.w;
      pk[q * 2 + 0] = (u32)f2bf(f.x) | ((u32)f2bf(f.y) << 16);
      pk[q * 2 + 1] = (u32)f2bf(f.z) | ((u32)f2bf(f.w) << 16);
    }
    *(uint4*)(dst)     = make_uint4(pk[0], pk[1], pk[2], pk[3]);
    *(uint4*)(dst + 8) = make_uint4(pk[4], pk[5], pk[6], pk[7]);
    #pragma unroll
    for (int d = 1; d < 64; d <<= 1) sa += __shfl_xor(sa, d);
    if (lane == 0) p.wn[v] = sqrtf(sa);
  }
  const long long tot = (long long)TT * NB * EE;
  for (long long i = gtid; i < tot; i += (long long)NWG * TPB) {
    int t = (int)(i / (NB * EE));
    int rr = (int)(i % (NB * EE));
    int b2 = rr / EE, k = rr % EE;
    float v = p.emb[(size_t)p.texts[b2 * TT + t] * EE + k];
    p.xT[((size_t)t * EE + k) * NB + b2] = v;
  }
}

__global__ void init_kernel(u32* bar, float* z0, float* z1, int n) {
  int g = blockIdx.x * blockDim.x + threadIdx.x;
  if (g < BAR_WORDS) bar[g] = 0u;
  for (int i = g; i < n; i += gridDim.x * blockDim.x) { z0[i] = 0.f; z1[i] = 0.f; }
}

// ================= coop mode: 1 encoder dispatch ===========================
__global__ void __launch_bounds__(TPB, 1) enc_coop_kernel(P p) {
  __shared__ __align__(16) char smem[EOFF + 16384];
  const int wg = blockIdx.x;
  const int dir = wg >> 7;
  const int ejjb = (wg & 127) * 4;
  u32 ebD = 0;
  enc_stage_weights(smem, dir, ejjb, p);
  __syncthreads();
  const float* bih = dir ? p.ebih1 : p.ebih0;
  const float* bhh = dir ? p.ebhh1 : p.ebhh0;
  float* hr = dir ? p.hrB : p.hrF;
  for (int t = 0; t < TT; t++) {
    const int te = dir ? (TT - 1 - t) : t;
    const float* hc = hr + (size_t)t * HEN * NB;        // fresh: plain reads
    float* ho = hr + (size_t)(t + 1) * HEN * NB;        // cst writes
    enc_step_body<true>(smem, ejjb, p.xT + (size_t)te * EE * NB,
                        bih, bhh, hc, ho, te, p.len);
    gbarx(p.bar + BD_GRP + ((wg >> 4) << 6),
          p.bar + BD_ROOT + dir * 64, p.bar + BD_EPO + dir * 64, ebD++, 16u, 8u);
  }
}

// ================= coop mode: 1 decoder dispatch ===========================
__global__ void __launch_bounds__(TPB, 1) dec_coop_kernel(P p) {
  extern __shared__ __align__(16) char smem[];
  const int wg = blockIdx.x, tid = threadIdx.x;
  const int gtid = wg * TPB + tid;
  u32 ebX = 0;
  // prologue: concat final enc states (cross-dispatch coherent, plain reads)
  for (int i = gtid; i < HD * NB; i += NWG * TPB) {
    int k = i / NB, b2 = i % NB;
    float v = (k < HEN) ? p.hrF[(size_t)TT * HEN * NB + (size_t)k * NB + b2]
                        : p.hrB[(size_t)TT * HEN * NB + (size_t)(k - HEN) * NB + b2];
    cst(p.hTdR + i, v);
  }
  if (gtid < NB) cst(p.tok + gtid, 1);   // sos
  gbarx(p.bar + BX_GRP + ((wg >> 4) << 6),
        p.bar + BX_ROOT, p.bar + BX_EPO, ebX++, 16u, 16u);

  for (int s = 0; s < DEC; s++) {
    const float* hc = p.hTdR + (size_t)s * HD * NB;       // fresh: plain
    float* ho = p.hTdR + (size_t)(s + 1) * HD * NB;       // cst
    u16* hbf_s = p.hbfR + (size_t)s * NB * HD;            // cst
    dec_gru_body<true>(p, (float*)(smem + LGOFF), wg * 4, hc, ho, hbf_s);
    gbarx(p.bar + BX_GRP + ((wg >> 4) << 6),
          p.bar + BX_ROOT, p.bar + BX_EPO, ebX++, 16u, 16u);
    dec_logits_body<true>(p, smem, hbf_s);                // hbf plain (fresh)
    gbarx(p.bar + BX_GRP + ((wg >> 4) << 6),
          p.bar + BX_ROOT, p.bar + BX_EPO, ebX++, 16u, 16u);
    if (wg < NB) dec_rescue_body<true>(p, smem, ho, s, wg);
    gbarx(p.bar + BX_GRP + ((wg >> 4) << 6),
          p.bar + BX_ROOT, p.bar + BX_EPO, ebX++, 16u, 16u);
  }
}

// ================= fallback mode: per-phase dispatches (round-6 path) ======
__global__ void __launch_bounds__(TPB, 1) enc_step_kernel(P p, int t) {
  __shared__ __align__(16) char smem[EOFF + 16384];
  const int wg = blockIdx.x;
  const int dir = wg >> 7;
  const int ejjb = (wg & 127) * 4;
  enc_stage_weights(smem, dir, ejjb, p);
  __syncthreads();
  const float* bih = dir ? p.ebih1 : p.ebih0;
  const float* bhh = dir ? p.ebhh1 : p.ebhh0;
  float* hbase = dir ? p.hTb : p.hTf;
  const int te = dir ? (TT - 1 - t) : t;
  const float* hc = hbase + (size_t)(t & 1) * HEN * NB;
  float* ho = hbase + (size_t)((t + 1) & 1) * HEN * NB;
  enc_step_body<false>(smem, ejjb, p.xT + (size_t)te * EE * NB,
                       bih, bhh, hc, ho, te, p.len);
}
__global__ void enc_join_kernel(P p) {
  int g = blockIdx.x * blockDim.x + threadIdx.x;
  int stride = gridDim.x * blockDim.x;
  for (int i = g; i < HD * NB; i += stride) {
    int k = i / NB, b2 = i % NB;
    float v = (k < HEN) ? p.hTf[(size_t)k * NB + b2]
                        : p.hTb[(size_t)(k - HEN) * NB + b2];
    p.hTd[i] = v;
  }
  if (g < NB) p.tok[g] = 1;
}
__global__ void __launch_bounds__(TPB, 1) dec_gru_kernel(P p, int s) {
  __shared__ __align__(16) float pb[4096];
  const float* hc = p.hTd + (size_t)(s & 1) * HD * NB;
  float* ho = p.hTd + (size_t)((s + 1) & 1) * HD * NB;
  dec_gru_body<false>(p, pb, blockIdx.x * 4, hc, ho, p.hbf);
}
__global__ void __launch_bounds__(TPB, 1) dec_logits_kernel(P p) {
  extern __shared__ __align__(16) char smem[];
  dec_logits_body<false>(p, smem, p.hbf);
}
__global__ void __launch_bounds__(TPB, 1) dec_rescue_kernel(P p, int s) {
  extern __shared__ __align__(16) char smem[];
  const float* ho = p.hTd + (size_t)((s + 1) & 1) * HD * NB;
  dec_rescue_body<false>(p, smem, ho, s, blockIdx.x);
}

extern "C" void kernel_launch(void* const* d_in, const int* in_sizes, int n_in,
                              void* d_out, int out_size, void* d_ws, size_t ws_size,
                              hipStream_t stream) {
  char* w = (char*)d_ws;
  size_t off = 0;
  auto carve = [&](size_t n) {
    void* q = w + off;
    off = (off + n + 255) & ~(size_t)255;
    return q;
  };
  P p;
  p.texts = (const int*)d_in[0];
  p.len   = (const int*)d_in[1];
  p.emb   = (const float*)d_in[2];
  p.ewih0 = (const float*)d_in[3];  p.ewhh0 = (const float*)d_in[4];
  p.ebih0 = (const float*)d_in[5];  p.ebhh0 = (const float*)d_in[6];
  p.ewih1 = (const float*)d_in[7];  p.ewhh1 = (const float*)d_in[8];
  p.ebih1 = (const float*)d_in[9];  p.ebhh1 = (const float*)d_in[10];
  p.dwih  = (const float*)d_in[11]; p.dwhh  = (const float*)d_in[12];
  p.dbih  = (const float*)d_in[13]; p.dbhh  = (const float*)d_in[14];
  p.outw  = (const float*)d_in[15]; p.outb  = (const float*)d_in[16];
  p.out   = (float*)d_out;
  p.owbf  = (u16*)carve((size_t)VV * HD * 2);
  p.xT    = (float*)carve((size_t)TT * EE * NB * 4);
  p.prt   = (u64*)carve((size_t)NB * NTLP * 8);
  p.tok   = (int*)carve(256);
  p.wn    = (float*)carve((size_t)VV * 4);
  p.bar   = (u32*)carve(BAR_WORDS * 4);
  size_t off_common = off;

  // try coop mode (rotated fresh buffers)
  p.hrF  = (float*)carve((size_t)(TT + 1) * HEN * NB * 4);
  p.hrB  = (float*)carve((size_t)(TT + 1) * HEN * NB * 4);
  p.hTdR = (float*)carve((size_t)(DEC + 1) * HD * NB * 4);
  p.hbfR = (u16*)carve((size_t)DEC * NB * HD * 2);
  bool coop = (off <= ws_size);
  if (!coop) {
    off = off_common;
    p.hTf = (float*)carve((size_t)2 * HEN * NB * 4);
    p.hTb = (float*)carve((size_t)2 * HEN * NB * 4);
    p.hTd = (float*)carve((size_t)2 * HD * NB * 4);
    p.hbf = (u16*)carve((size_t)NB * HD * 2);
    if (off > ws_size) return;  // workspace too small: fail visibly
  } else {
    p.hTf = p.hrF; p.hTb = p.hrB; p.hTd = p.hTdR; p.hbf = p.hbfR;
  }

  hipFuncSetAttribute((const void*)dec_coop_kernel,
                      hipFuncAttributeMaxDynamicSharedMemorySize, DSZ);
  hipFuncSetAttribute((const void*)dec_logits_kernel,
                      hipFuncAttributeMaxDynamicSharedMemorySize, DSZ);

  if (coop) {
    init_kernel<<<dim3(64), dim3(256), 0, stream>>>(p.bar, p.hrF, p.hrB, HEN * NB);
    prep_kernel<<<dim3(NWG), dim3(TPB), 0, stream>>>(p);
    void* args[] = { &p };
    hipError_t e = hipLaunchCooperativeKernel((void*)enc_coop_kernel,
                                              dim3(NWG), dim3(TPB), args, 0, stream);
    if (e != hipSuccess)
      enc_coop_kernel<<<dim3(NWG), dim3(TPB), 0, stream>>>(p);
    e = hipLaunchCooperativeKernel((void*)dec_coop_kernel,
                                   dim3(NWG), dim3(TPB), args, DSZ, stream);
    if (e != hipSuccess)
      dec_coop_kernel<<<dim3(NWG), dim3(TPB), DSZ, stream>>>(p);
  } else {
    init_kernel<<<dim3(64), dim3(256), 0, stream>>>(p.bar, p.hTf, p.hTb, 2 * HEN * NB);
    prep_kernel<<<dim3(NWG), dim3(TPB), 0, stream>>>(p);
    for (int t = 0; t < TT; t++)
      enc_step_kernel<<<dim3(NWG), dim3(TPB), 0, stream>>>(p, t);
    enc_join_kernel<<<dim3(64), dim3(256), 0, stream>>>(p);
    for (int s = 0; s < DEC; s++) {
      dec_gru_kernel<<<dim3(NWG), dim3(TPB), 0, stream>>>(p, s);
      dec_logits_kernel<<<dim3(NWG), dim3(TPB), DSZ, stream>>>(p);
      dec_rescue_kernel<<<dim3(NB), dim3(TPB), 0, stream>>>(p, s);
    }
  }
}